// Round 2
// baseline (416.680 us; speedup 1.0000x reference)
//
#include <hip/hip_runtime.h>
#include <math.h>

#define BDIM 2
#define TT 1024
#define NH 8
#define HD 64
#define NTOPK 16
#define NBH 16     // BDIM*NH
#define NTOK 16384 // NBH*TT

// ---------------------------------------------------------------------------
// Collapse the linear-linear pair MLPs into 128-dim fp64 vectors.
// ---------------------------------------------------------------------------
__global__ __launch_bounds__(256) void k_collapse64(
    const float* __restrict__ Wpi, const float* __restrict__ bpi,
    const float* __restrict__ Wpo, const float* __restrict__ bpo,
    const float* __restrict__ Wti, const float* __restrict__ bti,
    const float* __restrict__ Wto, const float* __restrict__ bto,
    double* __restrict__ wphid, double* __restrict__ wtaud,
    double* __restrict__ ccd) {
  int tid = threadIdx.x;
  int blk = blockIdx.x;
  if (blk < 16) {
    int r = blk * 16 + (tid >> 4);
    int l = tid & 15;
    double s = 0.;
    if (r < 128) {
      for (int i = 0; i < 32; ++i)
        s += (double)Wpi[r * 512 + l + 16 * i] * (double)Wpo[l + 16 * i];
    } else {
      int rr = r - 128;
      for (int i = 0; i < 16; ++i)
        s += (double)Wti[rr * 256 + l + 16 * i] * (double)Wto[l + 16 * i];
    }
#pragma unroll
    for (int off = 8; off >= 1; off >>= 1) s += __shfl_xor(s, off, 64);
    if (l == 0) {
      if (r < 128) wphid[r] = s;
      else wtaud[r - 128] = s;
    }
  } else {
    int lane = tid & 63;
    if (tid < 64) {
      double p = 0.;
      for (int c = lane; c < 512; c += 64) p += (double)bpi[c] * (double)Wpo[c];
#pragma unroll
      for (int off = 32; off >= 1; off >>= 1) p += __shfl_xor(p, off, 64);
      if (lane == 0) ccd[0] = p + (double)bpo[0];
    } else if (tid < 128) {
      double p = 0.;
      for (int c = lane; c < 256; c += 64) p += (double)bti[c] * (double)Wto[c];
#pragma unroll
      for (int off = 32; off >= 1; off >>= 1) p += __shfl_xor(p, off, 64);
      if (lane == 0) ccd[1] = p + (double)bto[0];
    }
  }
}

// ---------------------------------------------------------------------------
// Row-wave fp32 GEMM. Each wave owns 8 rows x 64 cols (lane = col).
// A operands are wave-uniform -> scalar loads (SMEM), off the LDS/VALU path;
// only B is staged in LDS (double-buffered, one barrier per K-step).
// LDS read ratio: 4 B per 16 FLOP = 0.25 B/FLOP (half-subscription).
// Per output element the accumulation chain is ONE fmaf per k, k ascending
// 0..511, bias added once at the end -> bit-identical rounding to the
// previous gemm_body (top-k selection depends on this).
// ---------------------------------------------------------------------------
__device__ __forceinline__ void gemm_rw_body(
    const float* __restrict__ A, const float* __restrict__ W,
    const float* __restrict__ bias, float* __restrict__ out,
    int bm, int bn, int mode) {
  __shared__ float Bs[2][32][64];
  const int tid = threadIdx.x;
  const int lane = tid & 63;
  const int wv = tid >> 6;
  const int row0 = bm + wv * 8;
  const float* Ar = A + (size_t)row0 * 512;

  // prologue: stage first B tile
#pragma unroll
  for (int i = 0; i < 2; ++i) {
    int idx = i * 256 + tid;
    int br = idx >> 4;          // 0..31 (k within tile)
    int bc = (idx & 15) << 2;   // 0..60 (col)
    *(float4*)&Bs[0][br][bc] = *(const float4*)&W[(size_t)br * 512 + bn + bc];
  }
  __syncthreads();

  float acc[8] = {0.f, 0.f, 0.f, 0.f, 0.f, 0.f, 0.f, 0.f};
  int cur = 0;
  for (int k0 = 0; k0 < 512; k0 += 32) {
    // issue next-tile staging early (hides HBM/L2 latency under compute)
    if (k0 + 32 < 512) {
#pragma unroll
      for (int i = 0; i < 2; ++i) {
        int idx = i * 256 + tid;
        int br = idx >> 4;
        int bc = (idx & 15) << 2;
        *(float4*)&Bs[cur ^ 1][br][bc] =
            *(const float4*)&W[(size_t)(k0 + 32 + br) * 512 + bn + bc];
      }
    }
#pragma unroll 2
    for (int kk4 = 0; kk4 < 8; ++kk4) {
      // A: 8 rows x 4 consecutive k — wave-uniform addresses -> s_load
      float a0[8], a1[8], a2[8], a3[8];
#pragma unroll
      for (int r = 0; r < 8; ++r) {
        float4 t = *(const float4*)&Ar[r * 512 + k0 + kk4 * 4];
        a0[r] = t.x; a1[r] = t.y; a2[r] = t.z; a3[r] = t.w;
      }
      float b0 = Bs[cur][kk4 * 4 + 0][lane];
      float b1 = Bs[cur][kk4 * 4 + 1][lane];
      float b2 = Bs[cur][kk4 * 4 + 2][lane];
      float b3 = Bs[cur][kk4 * 4 + 3][lane];
      // k order: kk4*4 + 0,1,2,3 — strictly ascending, one fmaf per k
#pragma unroll
      for (int r = 0; r < 8; ++r) acc[r] = fmaf(a0[r], b0, acc[r]);
#pragma unroll
      for (int r = 0; r < 8; ++r) acc[r] = fmaf(a1[r], b1, acc[r]);
#pragma unroll
      for (int r = 0; r < 8; ++r) acc[r] = fmaf(a2[r], b2, acc[r]);
#pragma unroll
      for (int r = 0; r < 8; ++r) acc[r] = fmaf(a3[r], b3, acc[r]);
    }
    __syncthreads();
    cur ^= 1;
  }

  const float bcol = bias[bn + lane];
#pragma unroll
  for (int r = 0; r < 8; ++r) {
    int row = row0 + r;
    float o = acc[r] + bcol;
    if (mode == 0) {
      out[(size_t)row * 512 + bn + lane] = o;
    } else {
      int bbk = row >> 10;
      int tt2 = row & 1023;
      int head = bn >> 6;
      out[(size_t)(((bbk * NH + head) * TT + tt2) << 6) + lane] = o;
    }
  }
}

__global__ __launch_bounds__(256) void k_gemm(
    const float* __restrict__ A, const float* __restrict__ W,
    const float* __restrict__ bias, float* __restrict__ out, int mode) {
  gemm_rw_body(A, W, bias, out, blockIdx.y * 32, blockIdx.x * 64, mode);
}

__global__ __launch_bounds__(256) void k_gemm_qkv(
    const float* __restrict__ A,
    const float* __restrict__ Wq, const float* __restrict__ bq,
    const float* __restrict__ Wk, const float* __restrict__ bk,
    const float* __restrict__ Wv, const float* __restrict__ bv,
    float* __restrict__ Qf, float* __restrict__ Kf, float* __restrict__ Vf) {
  int which = blockIdx.x >> 3;
  int bn = (blockIdx.x & 7) * 64;
  const float* W = (which == 0) ? Wq : (which == 1) ? Wk : Wv;
  const float* b = (which == 0) ? bq : (which == 1) ? bk : bv;
  float* out = (which == 0) ? Qf : (which == 1) ? Kf : Vf;
  gemm_rw_body(A, W, b, out, blockIdx.y * 32, bn, 1);
}

// ---------------------------------------------------------------------------
// Per-token scalars in fp64.
// ---------------------------------------------------------------------------
__global__ __launch_bounds__(256) void k_tokscal64(
    const float* __restrict__ Qg, const float* __restrict__ Kg,
    const double* __restrict__ wphid, const float* __restrict__ Wta,
    const float* __restrict__ Wtb, const double* __restrict__ wtaud,
    double4* __restrict__ sqd4, double4* __restrict__ skd4) {
  __shared__ double wp[128], wa[128], wb[128], wt[128];
  int tid = threadIdx.x;
  if (tid < 128) {
    wp[tid] = wphid[tid];
    wa[tid] = (double)Wta[tid];
    wb[tid] = (double)Wtb[tid];
    wt[tid] = wtaud[tid];
  }
  __syncthreads();
  int tok = blockIdx.x * 256 + tid;
  const float* qr = Qg + (size_t)tok * 64;
  const float* kr = Kg + (size_t)tok * 64;
  double sp = 0., sa = 0., sb = 0., st = 0.;
  double kp = 0., ka = 0., kb2 = 0., kt = 0.;
#pragma unroll
  for (int d = 0; d < 64; ++d) {
    double q = (double)qr[d];
    double k = (double)kr[d];
    sp += q * wp[d];
    sa += q * wa[d];
    sb += q * wb[d];
    st += q * wt[d];
    kp += k * wp[64 + d];
    ka += k * wa[64 + d];
    kb2 += k * wb[64 + d];
    kt += k * wt[64 + d];
  }
  sqd4[tok] = make_double4(sp, sa, sb, st);
  skd4[tok] = make_double4(kp, ka, kb2, kt);
}

// ---------------------------------------------------------------------------
// Score GEMM v2: Sc[bh][q][k] = sum_d Qf[bh][q][d] * Kf[bh][k][d].
// 128(q) x 128(k) tile, 8x8 register tile, BK=32, K-transpose fused into
// the B staging store (no separate k_trans / Kt buffer).
// d ascending, one fmaf per d per element — bit-identical rounding.
// Grid (8 ktiles, 8 qtiles, 16 bh), 256 threads.
// ---------------------------------------------------------------------------
__global__ __launch_bounds__(256) void k_score(
    const float* __restrict__ Qf, const float* __restrict__ Kf,
    float* __restrict__ Sc) {
  __shared__ float As[32][132];   // [d][q], padded
  __shared__ float Bs[32][132];   // [d][k], padded (transposed K)
  const int bn = blockIdx.x * 128;
  const int bm = blockIdx.y * 128;
  const int bh = blockIdx.z;
  const float* A = Qf + (size_t)bh * (TT * 64);
  const float* K = Kf + (size_t)bh * (TT * 64);
  float* out = Sc + (size_t)bh * (TT * 1024);
  const int tid = threadIdx.x;
  const int tx = tid & 15;        // k-group (8 k)
  const int ty = tid >> 4;        // q-group (8 q)
  float acc[8][8];
#pragma unroll
  for (int i = 0; i < 8; ++i)
#pragma unroll
    for (int j = 0; j < 8; ++j) acc[i][j] = 0.f;
  for (int k0 = 0; k0 < 64; k0 += 32) {
#pragma unroll
    for (int i = 0; i < 4; ++i) {
      int idx = i * 256 + tid;      // 0..1023
      int row = idx >> 3;           // 0..127
      int c4 = (idx & 7) << 2;      // 0..28
      float4 av = *(const float4*)&A[(size_t)(bm + row) * 64 + k0 + c4];
      As[c4 + 0][row] = av.x;
      As[c4 + 1][row] = av.y;
      As[c4 + 2][row] = av.z;
      As[c4 + 3][row] = av.w;
      float4 kv = *(const float4*)&K[(size_t)(bn + row) * 64 + k0 + c4];
      Bs[c4 + 0][row] = kv.x;
      Bs[c4 + 1][row] = kv.y;
      Bs[c4 + 2][row] = kv.z;
      Bs[c4 + 3][row] = kv.w;
    }
    __syncthreads();
#pragma unroll
    for (int kk = 0; kk < 32; ++kk) {
      float4 alo = *(const float4*)&As[kk][ty * 8];
      float4 ahi = *(const float4*)&As[kk][ty * 8 + 4];
      float4 blo = *(const float4*)&Bs[kk][tx * 8];
      float4 bhi = *(const float4*)&Bs[kk][tx * 8 + 4];
      float a[8] = {alo.x, alo.y, alo.z, alo.w, ahi.x, ahi.y, ahi.z, ahi.w};
      float b[8] = {blo.x, blo.y, blo.z, blo.w, bhi.x, bhi.y, bhi.z, bhi.w};
#pragma unroll
      for (int i = 0; i < 8; ++i)
#pragma unroll
        for (int j = 0; j < 8; ++j)
          acc[i][j] = fmaf(a[i], b[j], acc[i][j]);
    }
    __syncthreads();
  }
#pragma unroll
  for (int i = 0; i < 8; ++i) {
    float4 r0 = make_float4(acc[i][0], acc[i][1], acc[i][2], acc[i][3]);
    float4 r1 = make_float4(acc[i][4], acc[i][5], acc[i][6], acc[i][7]);
    size_t base = (size_t)(bm + ty * 8 + i) * 1024 + bn + tx * 8;
    *(float4*)&out[base] = r0;
    *(float4*)&out[base + 4] = r1;
  }
}

// ---------------------------------------------------------------------------
// Top-16 + fp32 logits/softmax/attend. One WAVE per query. Selection is
// bit-exact on the fp32 scores (value desc, global index asc).
//
// v2 selection (VALU-minimized, identical selected set & order):
//  * per-lane state = 4 groups of 4, each with tracked (max, argidx) where
//    strict '>' scans keep the EARLIEST index -> per-lane candidate is its
//    min-index maximum (matches jax.lax.top_k tie rule at every level).
//  * global max M via plain fmaxf butterfly (no compound predicate).
//  * winner index via __ballot(cv==M): single-tie fast path = one shuffle
//    from the ffs lane; multi-tie fallback = min-butterfly over candidate
//    indices (= min global index among value ties, exact tie semantics).
//  * J broadcast through readfirstlane -> owner/group/slot decode is
//    SCALAR, so the invalidate+rescan block is one uniform-branched group
//    (~11 VALU) instead of a 16-wide exec-masked rescan (~65 VALU).
// ---------------------------------------------------------------------------
__global__ __launch_bounds__(256) void k_topk(
    const float* __restrict__ Sc, const float* __restrict__ Vg,
    const double4* __restrict__ sqd4, const double4* __restrict__ skd4,
    const double* __restrict__ ccd, const float* __restrict__ btaP,
    const float* __restrict__ btbP, float* __restrict__ C) {
  const int tid = threadIdx.x;
  const int lane = tid & 63;
  const int wv = tid >> 6;
  const int qg = blockIdx.x * 4 + wv;   // 0..16383
  const int bh = qg >> 10;
  const int qa = qg & 1023;
  const int bb = bh >> 3;
  const int hh = bh & 7;
  const float* rowp = Sc + (size_t)qg * 1024;
  const float* Vbh = Vg + (size_t)bh * (TT * 64);

  // v[g*4+e] holds score at global key index g*256 + lane*4 + e
  float v[16];
#pragma unroll
  for (int g = 0; g < 4; ++g) {
    float4 t = *(const float4*)&rowp[g * 256 + lane * 4];
    v[g * 4 + 0] = t.x;
    v[g * 4 + 1] = t.y;
    v[g * 4 + 2] = t.z;
    v[g * 4 + 3] = t.w;
  }
  // per-group (max, global index of max); strict '>' keeps earliest index
  float gv[4];
  int gi[4];
  const int lbase = lane << 2;
#pragma unroll
  for (int g = 0; g < 4; ++g) {
    float nv = v[4 * g];
    int ne = 0;
#pragma unroll
    for (int e = 1; e < 4; ++e) {
      if (v[4 * g + e] > nv) { nv = v[4 * g + e]; ne = e; }
    }
    gv[g] = nv;
    gi[g] = (g << 8) | lbase | ne;
  }
  int myk = 0;  // lane it (<16) holds the it-th largest key index
#pragma unroll 1
  for (int it = 0; it < NTOPK; ++it) {
    // lane candidate: max over groups, earliest group on tie
    float cv = gv[0];
    int ci = gi[0];
#pragma unroll
    for (int g = 1; g < 4; ++g) {
      if (gv[g] > cv) { cv = gv[g]; ci = gi[g]; }
    }
    // global max value (cheap butterfly, value only)
    float M = cv;
#pragma unroll
    for (int off = 32; off >= 1; off >>= 1)
      M = fmaxf(M, __shfl_xor(M, off, 64));
    // resolve winning global index (min index among value ties)
    unsigned long long tied = __ballot(cv == M);
    int J;
    if (__popcll(tied) == 1) {
      int src = __ffsll(tied) - 1;
      J = __builtin_amdgcn_readfirstlane(__shfl(ci, src, 64));
    } else {
      int cj = (cv == M) ? ci : 0x7FFFFFFF;
#pragma unroll
      for (int off = 32; off >= 1; off >>= 1) {
        int oj = __shfl_xor(cj, off, 64);
        cj = (oj < cj) ? oj : cj;
      }
      J = __builtin_amdgcn_readfirstlane(cj);
    }
    if (lane == it) myk = J;
    // J is wave-uniform: decode owner/slot with scalar ops
    const int owner = (J >> 2) & 63;
    const int g2 = J >> 8;    // group (J < 1024)
    const int e2 = J & 3;     // element within group
    const bool isown = (lane == owner);
#pragma unroll
    for (int g = 0; g < 4; ++g) {
      if (g == g2) {  // uniform branch: only one group block executes
#pragma unroll
        for (int e = 0; e < 4; ++e) {
          if (e == e2) {  // uniform
            v[4 * g + e] = isown ? -INFINITY : v[4 * g + e];
          }
        }
        float nv = v[4 * g];
        int ne = 0;
#pragma unroll
        for (int e = 1; e < 4; ++e) {
          if (v[4 * g + e] > nv) { nv = v[4 * g + e]; ne = e; }
        }
        gv[g] = nv;
        gi[g] = (g << 8) | lbase | ne;
      }
    }
  }
  // fp32 smooth path (selection already fixed; ~1e-5 error << threshold)
  const double cphi = ccd[0];
  const double ctau = ccd[1];
  const double bta0 = (double)btaP[0];
  const double btb0 = (double)btbP[0];
  double4 sq = sqd4[qg];
  float logit = -INFINITY;
  if (lane < 16) {
    double4 sk = skd4[bh * TT + myk];
    float xs = (float)(sq.x + sk.x + cphi);
    float ta = (float)(sq.y + sk.y + bta0);
    float tb = (float)(sq.z + sk.z + btb0);
    float tl = (float)(sq.w + sk.w + ctau);
    float phi = 1.f / (1.f + __expf(-xs));
    float ti = 1.f / (1.f + __expf(-(ta + tb)));          // T_SCALAR = 1
    float tau = fmaxf(tl, 0.f) + log1pf(__expf(-fabsf(tl))) + 1e-6f;
    logit = phi / tau * (1.f - __expf(-tau * ti));
  }
  float m = logit;
#pragma unroll
  for (int off = 8; off >= 1; off >>= 1) m = fmaxf(m, __shfl_xor(m, off, 64));
  float e = (lane < 16) ? __expf(logit - m) : 0.f;
  float ssum = e;
#pragma unroll
  for (int off = 8; off >= 1; off >>= 1) ssum += __shfl_xor(ssum, off, 64);
  float w = e / ssum;
  float outv = 0.f;
#pragma unroll
  for (int k2 = 0; k2 < NTOPK; ++k2) {
    float wk = __shfl(w, k2, 64);
    int ik = __shfl(myk, k2, 64);
    outv = fmaf(wk, Vbh[(size_t)ik * 64 + lane], outv);
  }
  C[(bb * TT + qa) * 512 + hh * 64 + lane] = outv;
}

// ---------------------------------------------------------------------------
// Fallback fused attention (round-5 path) for small workspaces.
// ---------------------------------------------------------------------------
__global__ __launch_bounds__(256) void k_attn(
    const float* __restrict__ Qg, const float* __restrict__ Kg,
    const float* __restrict__ Vg, const double4* __restrict__ sqd4,
    const double4* __restrict__ skd4, const double* __restrict__ ccd,
    const float* __restrict__ btaP, const float* __restrict__ btbP,
    float* __restrict__ C) {
  __shared__ float qs[8][64];
  __shared__ float sc[8][1024];
  const int bh = blockIdx.y;
  const int q0 = blockIdx.x * 8;
  const int tid = threadIdx.x;
  const int lane = tid & 63;
  const int wv = tid >> 6;
  if (tid < 128) {
    int q = tid >> 4, d4 = (tid & 15) << 2;
    *(float4*)&qs[q][d4] = *(const float4*)&Qg[(size_t)(bh * TT + q0 + q) * 64 + d4];
  }
  __syncthreads();
#pragma unroll 1
  for (int c = 0; c < 4; ++c) {
    const int kb = (c * 4 + wv) * 64;
    const float* krow = &Kg[(size_t)(bh * TT + kb + lane) * 64];
    float4 kr[16];
#pragma unroll
    for (int i = 0; i < 16; ++i) kr[i] = *(const float4*)&krow[i * 4];
#pragma unroll
    for (int q = 0; q < 8; ++q) {
      float s = 0.f;
#pragma unroll
      for (int i = 0; i < 16; ++i) {
        float4 q4 = *(const float4*)&qs[q][i * 4];
        s = fmaf(q4.x, kr[i].x, s);
        s = fmaf(q4.y, kr[i].y, s);
        s = fmaf(q4.z, kr[i].z, s);
        s = fmaf(q4.w, kr[i].w, s);
      }
      sc[q][kb + lane] = s;
    }
  }
  __syncthreads();
  const double cphi = ccd[0];
  const double ctau = ccd[1];
  const double bta0 = (double)btaP[0];
  const double btb0 = (double)btbP[0];
  const int bb = bh >> 3;
  const int hh = bh & 7;
  const float* Vbh = Vg + (size_t)bh * (TT * 64);
#pragma unroll 1
  for (int qq = 0; qq < 2; ++qq) {
    const int ql = wv * 2 + qq;
    const int qa = q0 + ql;
    const float* rowp = &sc[ql][0];
    float v[16];
#pragma unroll
    for (int jj = 0; jj < 16; ++jj) v[jj] = rowp[jj * 64 + lane];
    float gv[4];
    int gj[4];
#pragma unroll
    for (int g = 0; g < 4; ++g) {
      gv[g] = v[4 * g];
      gj[g] = 4 * g;
#pragma unroll
      for (int e = 1; e < 4; ++e) {
        if (v[4 * g + e] > gv[g]) { gv[g] = v[4 * g + e]; gj[g] = 4 * g + e; }
      }
    }
    int myk = 0;
#pragma unroll 1
    for (int it = 0; it < NTOPK; ++it) {
      float bvv = gv[0];
      int bjj = gj[0];
#pragma unroll
      for (int g = 1; g < 4; ++g) {
        if (gv[g] > bvv) { bvv = gv[g]; bjj = gj[g]; }
      }
      int bj = bjj * 64 + lane;
#pragma unroll
      for (int off = 32; off >= 1; off >>= 1) {
        float ov = __shfl_xor(bvv, off, 64);
        int oj = __shfl_xor(bj, off, 64);
        if (ov > bvv || (ov == bvv && oj < bj)) { bvv = ov; bj = oj; }
      }
      if (lane == it) myk = bj;
      int owner = bj & 63;
      int slot = bj >> 6;
      if (lane == owner) {
#pragma unroll
        for (int jj = 0; jj < 16; ++jj)
          if (jj == slot) v[jj] = -INFINITY;
        int g2 = slot >> 2;
#pragma unroll
        for (int g = 0; g < 4; ++g) {
          if (g == g2) {
            float ngv = v[4 * g];
            int ngj = 4 * g;
#pragma unroll
            for (int e = 1; e < 4; ++e) {
              if (v[4 * g + e] > ngv) { ngv = v[4 * g + e]; ngj = 4 * g + e; }
            }
            gv[g] = ngv;
            gj[g] = ngj;
          }
        }
      }
    }
    double4 sq = sqd4[bh * TT + qa];
    double logit = -INFINITY;
    if (lane < 16) {
      double4 sk = skd4[bh * TT + myk];
      double phi = 1.0 / (1.0 + exp(-(sq.x + sk.x + cphi)));
      double ta = sq.y + sk.y + bta0;
      double tb = sq.z + sk.z + btb0;
      double ti = 1.0 / (1.0 + exp(-(ta * 1.0 + tb)));
      double tl = sq.w + sk.w + ctau;
      double tau = fmax(tl, 0.0) + log1p(exp(-fabs(tl))) + 1e-6;
      logit = phi / tau * (1.0 - exp(-tau * ti));
    }
    double m = logit;
#pragma unroll
    for (int off = 8; off >= 1; off >>= 1) {
      double om = __shfl_xor(m, off, 64);
      m = fmax(m, om);
    }
    double e = (lane < 16) ? exp(logit - m) : 0.0;
    double ssum = e;
#pragma unroll
    for (int off = 8; off >= 1; off >>= 1) ssum += __shfl_xor(ssum, off, 64);
    double w = e / ssum;
    double outv = 0.0;
#pragma unroll
    for (int k2 = 0; k2 < NTOPK; ++k2) {
      double wk = __shfl(w, k2, 64);
      int ik = __shfl(myk, k2, 64);
      outv += wk * (double)Vbh[(size_t)ik * 64 + lane];
    }
    C[(bb * TT + qa) * 512 + hh * 64 + lane] = (float)outv;
  }
}

// ---------------------------------------------------------------------------
extern "C" void kernel_launch(void* const* d_in, const int* in_sizes, int n_in,
                              void* d_out, int out_size, void* d_ws, size_t ws_size,
                              hipStream_t stream) {
  (void)in_sizes; (void)n_in; (void)out_size;
  const float* x   = (const float*)d_in[0];
  const float* Wq  = (const float*)d_in[1];
  const float* bq  = (const float*)d_in[2];
  const float* Wk  = (const float*)d_in[3];
  const float* bk  = (const float*)d_in[4];
  const float* Wv  = (const float*)d_in[5];
  const float* bv  = (const float*)d_in[6];
  const float* Wo  = (const float*)d_in[7];
  const float* bo  = (const float*)d_in[8];
  const float* Wpi = (const float*)d_in[9];
  const float* bpi = (const float*)d_in[10];
  const float* Wpo = (const float*)d_in[11];
  const float* bpo = (const float*)d_in[12];
  const float* Wta = (const float*)d_in[13];
  const float* bta = (const float*)d_in[14];
  const float* Wtb = (const float*)d_in[15];
  const float* btb = (const float*)d_in[16];
  const float* Wti = (const float*)d_in[17];
  const float* bti = (const float*)d_in[18];
  const float* Wto = (const float*)d_in[19];
  const float* bto = (const float*)d_in[20];

  double* wsd = (double*)d_ws;
  double4* sqd4 = (double4*)wsd;             // 65536 doubles
  double4* skd4 = (double4*)(wsd + 65536);   // 65536 doubles
  double* wphid = wsd + 131072;              // 128
  double* wtaud = wsd + 131200;              // 128
  double* ccd   = wsd + 131328;              // 2 (pad to 131332)
  float* fs = (float*)(wsd + 131332);
  float* Qf = fs;                  // 1,048,576 floats
  float* Kf = fs + 1048576;
  float* Vf = fs + 2097152;
  float* Cf = fs + 3145728;
  float* Sc = fs + 4194304;        // 16,777,216 floats (scores, 64 MB)
  const size_t need = (size_t)131332 * 8 + (size_t)(4194304 + 16777216) * 4;

  hipLaunchKernelGGL(k_collapse64, dim3(17), dim3(256), 0, stream,
                     Wpi, bpi, Wpo, bpo, Wti, bti, Wto, bto, wphid, wtaud, ccd);
  hipLaunchKernelGGL(k_gemm_qkv, dim3(24, 64), dim3(256), 0, stream,
                     x, Wq, bq, Wk, bk, Wv, bv, Qf, Kf, Vf);
  hipLaunchKernelGGL(k_tokscal64, dim3(NTOK / 256), dim3(256), 0, stream,
                     Qf, Kf, wphid, Wta, Wtb, wtaud, sqd4, skd4);
  if (ws_size >= need) {
    hipLaunchKernelGGL(k_score, dim3(8, 8, 16), dim3(256), 0, stream, Qf, Kf, Sc);
    hipLaunchKernelGGL(k_topk, dim3(NTOK / 4), dim3(256), 0, stream,
                       Sc, Vf, sqd4, skd4, ccd, bta, btb, Cf);
  } else {
    hipLaunchKernelGGL(k_attn, dim3(TT / 8, NBH), dim3(256), 0, stream,
                       Qf, Kf, Vf, sqd4, skd4, ccd, bta, btb, Cf);
  }
  hipLaunchKernelGGL(k_gemm, dim3(8, 64), dim3(256), 0, stream,
                     Cf, Wo, bo, (float*)d_out, 0);
}

// Round 3
// 247.287 us; speedup vs baseline: 1.6850x; 1.6850x over previous
//
#include <hip/hip_runtime.h>
#include <math.h>

#define BDIM 2
#define TT 1024
#define NH 8
#define HD 64
#define NTOPK 16
#define NBH 16     // BDIM*NH
#define NTOK 16384 // NBH*TT

// ---------------------------------------------------------------------------
// Collapse the linear-linear pair MLPs into 128-dim fp64 vectors.
// ---------------------------------------------------------------------------
__global__ __launch_bounds__(256) void k_collapse64(
    const float* __restrict__ Wpi, const float* __restrict__ bpi,
    const float* __restrict__ Wpo, const float* __restrict__ bpo,
    const float* __restrict__ Wti, const float* __restrict__ bti,
    const float* __restrict__ Wto, const float* __restrict__ bto,
    double* __restrict__ wphid, double* __restrict__ wtaud,
    double* __restrict__ ccd) {
  int tid = threadIdx.x;
  int blk = blockIdx.x;
  if (blk < 16) {
    int r = blk * 16 + (tid >> 4);
    int l = tid & 15;
    double s = 0.;
    if (r < 128) {
      for (int i = 0; i < 32; ++i)
        s += (double)Wpi[r * 512 + l + 16 * i] * (double)Wpo[l + 16 * i];
    } else {
      int rr = r - 128;
      for (int i = 0; i < 16; ++i)
        s += (double)Wti[rr * 256 + l + 16 * i] * (double)Wto[l + 16 * i];
    }
#pragma unroll
    for (int off = 8; off >= 1; off >>= 1) s += __shfl_xor(s, off, 64);
    if (l == 0) {
      if (r < 128) wphid[r] = s;
      else wtaud[r - 128] = s;
    }
  } else {
    int lane = tid & 63;
    if (tid < 64) {
      double p = 0.;
      for (int c = lane; c < 512; c += 64) p += (double)bpi[c] * (double)Wpo[c];
#pragma unroll
      for (int off = 32; off >= 1; off >>= 1) p += __shfl_xor(p, off, 64);
      if (lane == 0) ccd[0] = p + (double)bpo[0];
    } else if (tid < 128) {
      double p = 0.;
      for (int c = lane; c < 256; c += 64) p += (double)bti[c] * (double)Wto[c];
#pragma unroll
      for (int off = 32; off >= 1; off >>= 1) p += __shfl_xor(p, off, 64);
      if (lane == 0) ccd[1] = p + (double)bto[0];
    }
  }
}

// ---------------------------------------------------------------------------
// fp32 GEMM, strict sequential-k fp32 FMA per output element (BLAS-order —
// this rounding pattern makes top-k selection match the reference).
// R3: double-buffered LDS + 2-deep register prefetch, ONE barrier per
// K-step. Iteration s: write regs(tile s+1)->buf[(s+1)&1], issue loads
// (tile s+2)->regs, compute buf[s&1], barrier. FMA chain per output is
// unchanged (k ascending 0..511, one fmaf per k) -> bit-identical.
// ---------------------------------------------------------------------------
__device__ __forceinline__ void gemm_body(
    const float* __restrict__ A, const float* __restrict__ W,
    const float* __restrict__ bias, float* __restrict__ out,
    int bm, int bn, int mode) {
  __shared__ float As[2][32][68];
  __shared__ float Bs[2][32][64];
  const int tid = threadIdx.x;
  const int tx = tid & 15;
  const int ty = tid >> 4;
  // staging coordinates (same mapping as the proven 54us kernel)
  const int ar0 = tid >> 3;            // 0..31
  const int ar1 = 32 + (tid >> 3);     // 32..63
  const int ac4 = (tid & 7) << 2;      // 0..28
  const int br0 = tid >> 4;            // 0..15
  const int br1 = 16 + (tid >> 4);     // 16..31
  const int bc = (tid & 15) << 2;      // 0..60

  float4 ra0, ra1, rb0, rb1;
  // ---- load tile 0 -> regs
  ra0 = *(const float4*)&A[(size_t)(bm + ar0) * 512 + ac4];
  ra1 = *(const float4*)&A[(size_t)(bm + ar1) * 512 + ac4];
  rb0 = *(const float4*)&W[(size_t)br0 * 512 + bn + bc];
  rb1 = *(const float4*)&W[(size_t)br1 * 512 + bn + bc];
  // ---- write tile 0 -> buf 0
  As[0][ac4 + 0][ar0] = ra0.x; As[0][ac4 + 1][ar0] = ra0.y;
  As[0][ac4 + 2][ar0] = ra0.z; As[0][ac4 + 3][ar0] = ra0.w;
  As[0][ac4 + 0][ar1] = ra1.x; As[0][ac4 + 1][ar1] = ra1.y;
  As[0][ac4 + 2][ar1] = ra1.z; As[0][ac4 + 3][ar1] = ra1.w;
  *(float4*)&Bs[0][br0][bc] = rb0;
  *(float4*)&Bs[0][br1][bc] = rb1;
  // ---- load tile 1 -> regs
  ra0 = *(const float4*)&A[(size_t)(bm + ar0) * 512 + 32 + ac4];
  ra1 = *(const float4*)&A[(size_t)(bm + ar1) * 512 + 32 + ac4];
  rb0 = *(const float4*)&W[(size_t)(32 + br0) * 512 + bn + bc];
  rb1 = *(const float4*)&W[(size_t)(32 + br1) * 512 + bn + bc];
  __syncthreads();

  float acc[4][4] = {{0.f, 0.f, 0.f, 0.f}};
#pragma unroll 1
  for (int step = 0; step < 16; ++step) {
    const int cur = step & 1;
    if (step < 15) {
      const int nb = cur ^ 1;
      // write prefetched tile (step+1) to the other buffer
      As[nb][ac4 + 0][ar0] = ra0.x; As[nb][ac4 + 1][ar0] = ra0.y;
      As[nb][ac4 + 2][ar0] = ra0.z; As[nb][ac4 + 3][ar0] = ra0.w;
      As[nb][ac4 + 0][ar1] = ra1.x; As[nb][ac4 + 1][ar1] = ra1.y;
      As[nb][ac4 + 2][ar1] = ra1.z; As[nb][ac4 + 3][ar1] = ra1.w;
      *(float4*)&Bs[nb][br0][bc] = rb0;
      *(float4*)&Bs[nb][br1][bc] = rb1;
    }
    if (step < 14) {
      const int k0 = (step + 2) * 32;
      ra0 = *(const float4*)&A[(size_t)(bm + ar0) * 512 + k0 + ac4];
      ra1 = *(const float4*)&A[(size_t)(bm + ar1) * 512 + k0 + ac4];
      rb0 = *(const float4*)&W[(size_t)(k0 + br0) * 512 + bn + bc];
      rb1 = *(const float4*)&W[(size_t)(k0 + br1) * 512 + bn + bc];
    }
#pragma unroll
    for (int kk = 0; kk < 32; ++kk) {
      float4 a = *(const float4*)&As[cur][kk][ty * 4];
      float4 b = *(const float4*)&Bs[cur][kk][tx << 2];
      acc[0][0] = fmaf(a.x, b.x, acc[0][0]);
      acc[0][1] = fmaf(a.x, b.y, acc[0][1]);
      acc[0][2] = fmaf(a.x, b.z, acc[0][2]);
      acc[0][3] = fmaf(a.x, b.w, acc[0][3]);
      acc[1][0] = fmaf(a.y, b.x, acc[1][0]);
      acc[1][1] = fmaf(a.y, b.y, acc[1][1]);
      acc[1][2] = fmaf(a.y, b.z, acc[1][2]);
      acc[1][3] = fmaf(a.y, b.w, acc[1][3]);
      acc[2][0] = fmaf(a.z, b.x, acc[2][0]);
      acc[2][1] = fmaf(a.z, b.y, acc[2][1]);
      acc[2][2] = fmaf(a.z, b.z, acc[2][2]);
      acc[2][3] = fmaf(a.z, b.w, acc[2][3]);
      acc[3][0] = fmaf(a.w, b.x, acc[3][0]);
      acc[3][1] = fmaf(a.w, b.y, acc[3][1]);
      acc[3][2] = fmaf(a.w, b.z, acc[3][2]);
      acc[3][3] = fmaf(a.w, b.w, acc[3][3]);
    }
    __syncthreads();
  }
#pragma unroll
  for (int i = 0; i < 4; ++i) {
    int row = bm + ty * 4 + i;
    float4 r;
    r.x = acc[i][0] + bias[bn + tx * 4 + 0];
    r.y = acc[i][1] + bias[bn + tx * 4 + 1];
    r.z = acc[i][2] + bias[bn + tx * 4 + 2];
    r.w = acc[i][3] + bias[bn + tx * 4 + 3];
    if (mode == 0) {
      *(float4*)&out[(size_t)row * 512 + bn + tx * 4] = r;
    } else {
      int bb = row >> 10;
      int tt2 = row & 1023;
      int head = bn >> 6;
      *(float4*)&out[(size_t)(((bb * NH + head) * TT + tt2) << 6) + tx * 4] = r;
    }
  }
}

__global__ __launch_bounds__(256) void k_gemm(
    const float* __restrict__ A, const float* __restrict__ W,
    const float* __restrict__ bias, float* __restrict__ out, int mode) {
  gemm_body(A, W, bias, out, blockIdx.y * 64, blockIdx.x * 64, mode);
}

__global__ __launch_bounds__(256) void k_gemm_qkv(
    const float* __restrict__ A,
    const float* __restrict__ Wq, const float* __restrict__ bq,
    const float* __restrict__ Wk, const float* __restrict__ bk,
    const float* __restrict__ Wv, const float* __restrict__ bv,
    float* __restrict__ Qf, float* __restrict__ Kf, float* __restrict__ Vf) {
  int which = blockIdx.x >> 3;
  int bn = (blockIdx.x & 7) * 64;
  const float* W = (which == 0) ? Wq : (which == 1) ? Wk : Wv;
  const float* b = (which == 0) ? bq : (which == 1) ? bk : bv;
  float* out = (which == 0) ? Qf : (which == 1) ? Kf : Vf;
  gemm_body(A, W, b, out, blockIdx.y * 64, bn, 1);
}

// ---------------------------------------------------------------------------
// Per-token scalars in fp64.
// ---------------------------------------------------------------------------
__global__ __launch_bounds__(256) void k_tokscal64(
    const float* __restrict__ Qg, const float* __restrict__ Kg,
    const double* __restrict__ wphid, const float* __restrict__ Wta,
    const float* __restrict__ Wtb, const double* __restrict__ wtaud,
    double4* __restrict__ sqd4, double4* __restrict__ skd4) {
  __shared__ double wp[128], wa[128], wb[128], wt[128];
  int tid = threadIdx.x;
  if (tid < 128) {
    wp[tid] = wphid[tid];
    wa[tid] = (double)Wta[tid];
    wb[tid] = (double)Wtb[tid];
    wt[tid] = wtaud[tid];
  }
  __syncthreads();
  int tok = blockIdx.x * 256 + tid;
  const float* qr = Qg + (size_t)tok * 64;
  const float* kr = Kg + (size_t)tok * 64;
  double sp = 0., sa = 0., sb = 0., st = 0.;
  double kp = 0., ka = 0., kb2 = 0., kt = 0.;
#pragma unroll
  for (int d = 0; d < 64; ++d) {
    double q = (double)qr[d];
    double k = (double)kr[d];
    sp += q * wp[d];
    sa += q * wa[d];
    sb += q * wb[d];
    st += q * wt[d];
    kp += k * wp[64 + d];
    ka += k * wa[64 + d];
    kb2 += k * wb[64 + d];
    kt += k * wt[64 + d];
  }
  sqd4[tok] = make_double4(sp, sa, sb, st);
  skd4[tok] = make_double4(kp, ka, kb2, kt);
}

// ---------------------------------------------------------------------------
// Score GEMM v2: Sc[bh][q][k] = sum_d Qf[bh][q][d] * Kf[bh][k][d].
// 128(q) x 128(k) tile, 8x8 register tile, BK=32, K-transpose fused into
// the B staging store (no separate k_trans / Kt buffer).
// d ascending, one fmaf per d per element — bit-identical rounding.
// Grid (8 ktiles, 8 qtiles, 16 bh), 256 threads.
// ---------------------------------------------------------------------------
__global__ __launch_bounds__(256) void k_score(
    const float* __restrict__ Qf, const float* __restrict__ Kf,
    float* __restrict__ Sc) {
  __shared__ float As[32][132];   // [d][q], padded
  __shared__ float Bs[32][132];   // [d][k], padded (transposed K)
  const int bn = blockIdx.x * 128;
  const int bm = blockIdx.y * 128;
  const int bh = blockIdx.z;
  const float* A = Qf + (size_t)bh * (TT * 64);
  const float* K = Kf + (size_t)bh * (TT * 64);
  float* out = Sc + (size_t)bh * (TT * 1024);
  const int tid = threadIdx.x;
  const int tx = tid & 15;        // k-group (8 k)
  const int ty = tid >> 4;        // q-group (8 q)
  float acc[8][8];
#pragma unroll
  for (int i = 0; i < 8; ++i)
#pragma unroll
    for (int j = 0; j < 8; ++j) acc[i][j] = 0.f;
  for (int k0 = 0; k0 < 64; k0 += 32) {
#pragma unroll
    for (int i = 0; i < 4; ++i) {
      int idx = i * 256 + tid;      // 0..1023
      int row = idx >> 3;           // 0..127
      int c4 = (idx & 7) << 2;      // 0..28
      float4 av = *(const float4*)&A[(size_t)(bm + row) * 64 + k0 + c4];
      As[c4 + 0][row] = av.x;
      As[c4 + 1][row] = av.y;
      As[c4 + 2][row] = av.z;
      As[c4 + 3][row] = av.w;
      float4 kv = *(const float4*)&K[(size_t)(bn + row) * 64 + k0 + c4];
      Bs[c4 + 0][row] = kv.x;
      Bs[c4 + 1][row] = kv.y;
      Bs[c4 + 2][row] = kv.z;
      Bs[c4 + 3][row] = kv.w;
    }
    __syncthreads();
#pragma unroll
    for (int kk = 0; kk < 32; ++kk) {
      float4 alo = *(const float4*)&As[kk][ty * 8];
      float4 ahi = *(const float4*)&As[kk][ty * 8 + 4];
      float4 blo = *(const float4*)&Bs[kk][tx * 8];
      float4 bhi = *(const float4*)&Bs[kk][tx * 8 + 4];
      float a[8] = {alo.x, alo.y, alo.z, alo.w, ahi.x, ahi.y, ahi.z, ahi.w};
      float b[8] = {blo.x, blo.y, blo.z, blo.w, bhi.x, bhi.y, bhi.z, bhi.w};
#pragma unroll
      for (int i = 0; i < 8; ++i)
#pragma unroll
        for (int j = 0; j < 8; ++j)
          acc[i][j] = fmaf(a[i], b[j], acc[i][j]);
    }
    __syncthreads();
  }
#pragma unroll
  for (int i = 0; i < 8; ++i) {
    float4 r0 = make_float4(acc[i][0], acc[i][1], acc[i][2], acc[i][3]);
    float4 r1 = make_float4(acc[i][4], acc[i][5], acc[i][6], acc[i][7]);
    size_t base = (size_t)(bm + ty * 8 + i) * 1024 + bn + tx * 8;
    *(float4*)&out[base] = r0;
    *(float4*)&out[base + 4] = r1;
  }
}

// ---------------------------------------------------------------------------
// Top-16 + fp32 logits/softmax/attend. One WAVE per query. Selection is
// bit-exact on the fp32 scores (value desc, global index asc).
// v2 selection: scalarized invalidation via readfirstlane(J).
// ---------------------------------------------------------------------------
__global__ __launch_bounds__(256) void k_topk(
    const float* __restrict__ Sc, const float* __restrict__ Vg,
    const double4* __restrict__ sqd4, const double4* __restrict__ skd4,
    const double* __restrict__ ccd, const float* __restrict__ btaP,
    const float* __restrict__ btbP, float* __restrict__ C) {
  const int tid = threadIdx.x;
  const int lane = tid & 63;
  const int wv = tid >> 6;
  const int qg = blockIdx.x * 4 + wv;   // 0..16383
  const int bh = qg >> 10;
  const int qa = qg & 1023;
  const int bb = bh >> 3;
  const int hh = bh & 7;
  const float* rowp = Sc + (size_t)qg * 1024;
  const float* Vbh = Vg + (size_t)bh * (TT * 64);

  // v[g*4+e] holds score at global key index g*256 + lane*4 + e
  float v[16];
#pragma unroll
  for (int g = 0; g < 4; ++g) {
    float4 t = *(const float4*)&rowp[g * 256 + lane * 4];
    v[g * 4 + 0] = t.x;
    v[g * 4 + 1] = t.y;
    v[g * 4 + 2] = t.z;
    v[g * 4 + 3] = t.w;
  }
  // per-group (max, global index of max); strict '>' keeps earliest index
  float gv[4];
  int gi[4];
  const int lbase = lane << 2;
#pragma unroll
  for (int g = 0; g < 4; ++g) {
    float nv = v[4 * g];
    int ne = 0;
#pragma unroll
    for (int e = 1; e < 4; ++e) {
      if (v[4 * g + e] > nv) { nv = v[4 * g + e]; ne = e; }
    }
    gv[g] = nv;
    gi[g] = (g << 8) | lbase | ne;
  }
  int myk = 0;  // lane it (<16) holds the it-th largest key index
#pragma unroll 1
  for (int it = 0; it < NTOPK; ++it) {
    // lane candidate: max over groups, earliest group on tie
    float cv = gv[0];
    int ci = gi[0];
#pragma unroll
    for (int g = 1; g < 4; ++g) {
      if (gv[g] > cv) { cv = gv[g]; ci = gi[g]; }
    }
    // global max value (cheap butterfly, value only)
    float M = cv;
#pragma unroll
    for (int off = 32; off >= 1; off >>= 1)
      M = fmaxf(M, __shfl_xor(M, off, 64));
    // resolve winning global index (min index among value ties)
    unsigned long long tied = __ballot(cv == M);
    int J;
    if (__popcll(tied) == 1) {
      int src = __ffsll(tied) - 1;
      J = __builtin_amdgcn_readfirstlane(__shfl(ci, src, 64));
    } else {
      int cj = (cv == M) ? ci : 0x7FFFFFFF;
#pragma unroll
      for (int off = 32; off >= 1; off >>= 1) {
        int oj = __shfl_xor(cj, off, 64);
        cj = (oj < cj) ? oj : cj;
      }
      J = __builtin_amdgcn_readfirstlane(cj);
    }
    if (lane == it) myk = J;
    // J is wave-uniform: decode owner/slot with scalar ops
    const int owner = (J >> 2) & 63;
    const int g2 = J >> 8;    // group (J < 1024)
    const int e2 = J & 3;     // element within group
    const bool isown = (lane == owner);
#pragma unroll
    for (int g = 0; g < 4; ++g) {
      if (g == g2) {  // uniform branch: only one group block executes
#pragma unroll
        for (int e = 0; e < 4; ++e) {
          if (e == e2) {  // uniform
            v[4 * g + e] = isown ? -INFINITY : v[4 * g + e];
          }
        }
        float nv = v[4 * g];
        int ne = 0;
#pragma unroll
        for (int e = 1; e < 4; ++e) {
          if (v[4 * g + e] > nv) { nv = v[4 * g + e]; ne = e; }
        }
        gv[g] = nv;
        gi[g] = (g << 8) | lbase | ne;
      }
    }
  }
  // fp32 smooth path (selection already fixed; ~1e-5 error << threshold)
  const double cphi = ccd[0];
  const double ctau = ccd[1];
  const double bta0 = (double)btaP[0];
  const double btb0 = (double)btbP[0];
  double4 sq = sqd4[qg];
  float logit = -INFINITY;
  if (lane < 16) {
    double4 sk = skd4[bh * TT + myk];
    float xs = (float)(sq.x + sk.x + cphi);
    float ta = (float)(sq.y + sk.y + bta0);
    float tb = (float)(sq.z + sk.z + btb0);
    float tl = (float)(sq.w + sk.w + ctau);
    float phi = 1.f / (1.f + __expf(-xs));
    float ti = 1.f / (1.f + __expf(-(ta + tb)));          // T_SCALAR = 1
    float tau = fmaxf(tl, 0.f) + log1pf(__expf(-fabsf(tl))) + 1e-6f;
    logit = phi / tau * (1.f - __expf(-tau * ti));
  }
  float m = logit;
#pragma unroll
  for (int off = 8; off >= 1; off >>= 1) m = fmaxf(m, __shfl_xor(m, off, 64));
  float e = (lane < 16) ? __expf(logit - m) : 0.f;
  float ssum = e;
#pragma unroll
  for (int off = 8; off >= 1; off >>= 1) ssum += __shfl_xor(ssum, off, 64);
  float w = e / ssum;
  float outv = 0.f;
#pragma unroll
  for (int k2 = 0; k2 < NTOPK; ++k2) {
    float wk = __shfl(w, k2, 64);
    int ik = __shfl(myk, k2, 64);
    outv = fmaf(wk, Vbh[(size_t)ik * 64 + lane], outv);
  }
  C[(bb * TT + qa) * 512 + hh * 64 + lane] = outv;
}

// ---------------------------------------------------------------------------
// Fallback fused attention (round-5 path) for small workspaces.
// ---------------------------------------------------------------------------
__global__ __launch_bounds__(256) void k_attn(
    const float* __restrict__ Qg, const float* __restrict__ Kg,
    const float* __restrict__ Vg, const double4* __restrict__ sqd4,
    const double4* __restrict__ skd4, const double* __restrict__ ccd,
    const float* __restrict__ btaP, const float* __restrict__ btbP,
    float* __restrict__ C) {
  __shared__ float qs[8][64];
  __shared__ float sc[8][1024];
  const int bh = blockIdx.y;
  const int q0 = blockIdx.x * 8;
  const int tid = threadIdx.x;
  const int lane = tid & 63;
  const int wv = tid >> 6;
  if (tid < 128) {
    int q = tid >> 4, d4 = (tid & 15) << 2;
    *(float4*)&qs[q][d4] = *(const float4*)&Qg[(size_t)(bh * TT + q0 + q) * 64 + d4];
  }
  __syncthreads();
#pragma unroll 1
  for (int c = 0; c < 4; ++c) {
    const int kb = (c * 4 + wv) * 64;
    const float* krow = &Kg[(size_t)(bh * TT + kb + lane) * 64];
    float4 kr[16];
#pragma unroll
    for (int i = 0; i < 16; ++i) kr[i] = *(const float4*)&krow[i * 4];
#pragma unroll
    for (int q = 0; q < 8; ++q) {
      float s = 0.f;
#pragma unroll
      for (int i = 0; i < 16; ++i) {
        float4 q4 = *(const float4*)&qs[q][i * 4];
        s = fmaf(q4.x, kr[i].x, s);
        s = fmaf(q4.y, kr[i].y, s);
        s = fmaf(q4.z, kr[i].z, s);
        s = fmaf(q4.w, kr[i].w, s);
      }
      sc[q][kb + lane] = s;
    }
  }
  __syncthreads();
  const double cphi = ccd[0];
  const double ctau = ccd[1];
  const double bta0 = (double)btaP[0];
  const double btb0 = (double)btbP[0];
  const int bb = bh >> 3;
  const int hh = bh & 7;
  const float* Vbh = Vg + (size_t)bh * (TT * 64);
#pragma unroll 1
  for (int qq = 0; qq < 2; ++qq) {
    const int ql = wv * 2 + qq;
    const int qa = q0 + ql;
    const float* rowp = &sc[ql][0];
    float v[16];
#pragma unroll
    for (int jj = 0; jj < 16; ++jj) v[jj] = rowp[jj * 64 + lane];
    float gv[4];
    int gj[4];
#pragma unroll
    for (int g = 0; g < 4; ++g) {
      gv[g] = v[4 * g];
      gj[g] = 4 * g;
#pragma unroll
      for (int e = 1; e < 4; ++e) {
        if (v[4 * g + e] > gv[g]) { gv[g] = v[4 * g + e]; gj[g] = 4 * g + e; }
      }
    }
    int myk = 0;
#pragma unroll 1
    for (int it = 0; it < NTOPK; ++it) {
      float bvv = gv[0];
      int bjj = gj[0];
#pragma unroll
      for (int g = 1; g < 4; ++g) {
        if (gv[g] > bvv) { bvv = gv[g]; bjj = gj[g]; }
      }
      int bj = bjj * 64 + lane;
#pragma unroll
      for (int off = 32; off >= 1; off >>= 1) {
        float ov = __shfl_xor(bvv, off, 64);
        int oj = __shfl_xor(bj, off, 64);
        if (ov > bvv || (ov == bvv && oj < bj)) { bvv = ov; bj = oj; }
      }
      if (lane == it) myk = bj;
      int owner = bj & 63;
      int slot = bj >> 6;
      if (lane == owner) {
#pragma unroll
        for (int jj = 0; jj < 16; ++jj)
          if (jj == slot) v[jj] = -INFINITY;
        int g2 = slot >> 2;
#pragma unroll
        for (int g = 0; g < 4; ++g) {
          if (g == g2) {
            float ngv = v[4 * g];
            int ngj = 4 * g;
#pragma unroll
            for (int e = 1; e < 4; ++e) {
              if (v[4 * g + e] > ngv) { ngv = v[4 * g + e]; ngj = 4 * g + e; }
            }
            gv[g] = ngv;
            gj[g] = ngj;
          }
        }
      }
    }
    double4 sq = sqd4[bh * TT + qa];
    double logit = -INFINITY;
    if (lane < 16) {
      double4 sk = skd4[bh * TT + myk];
      double phi = 1.0 / (1.0 + exp(-(sq.x + sk.x + cphi)));
      double ta = sq.y + sk.y + bta0;
      double tb = sq.z + sk.z + btb0;
      double ti = 1.0 / (1.0 + exp(-(ta * 1.0 + tb)));
      double tl = sq.w + sk.w + ctau;
      double tau = fmax(tl, 0.0) + log1p(exp(-fabs(tl))) + 1e-6;
      logit = phi / tau * (1.0 - exp(-tau * ti));
    }
    double m = logit;
#pragma unroll
    for (int off = 8; off >= 1; off >>= 1) {
      double om = __shfl_xor(m, off, 64);
      m = fmax(m, om);
    }
    double e = (lane < 16) ? exp(logit - m) : 0.0;
    double ssum = e;
#pragma unroll
    for (int off = 8; off >= 1; off >>= 1) ssum += __shfl_xor(ssum, off, 64);
    double w = e / ssum;
    double outv = 0.0;
#pragma unroll
    for (int k2 = 0; k2 < NTOPK; ++k2) {
      double wk = __shfl(w, k2, 64);
      int ik = __shfl(myk, k2, 64);
      outv += wk * (double)Vbh[(size_t)ik * 64 + lane];
    }
    C[(bb * TT + qa) * 512 + hh * 64 + lane] = (float)outv;
  }
}

// ---------------------------------------------------------------------------
extern "C" void kernel_launch(void* const* d_in, const int* in_sizes, int n_in,
                              void* d_out, int out_size, void* d_ws, size_t ws_size,
                              hipStream_t stream) {
  (void)in_sizes; (void)n_in; (void)out_size;
  const float* x   = (const float*)d_in[0];
  const float* Wq  = (const float*)d_in[1];
  const float* bq  = (const float*)d_in[2];
  const float* Wk  = (const float*)d_in[3];
  const float* bk  = (const float*)d_in[4];
  const float* Wv  = (const float*)d_in[5];
  const float* bv  = (const float*)d_in[6];
  const float* Wo  = (const float*)d_in[7];
  const float* bo  = (const float*)d_in[8];
  const float* Wpi = (const float*)d_in[9];
  const float* bpi = (const float*)d_in[10];
  const float* Wpo = (const float*)d_in[11];
  const float* bpo = (const float*)d_in[12];
  const float* Wta = (const float*)d_in[13];
  const float* bta = (const float*)d_in[14];
  const float* Wtb = (const float*)d_in[15];
  const float* btb = (const float*)d_in[16];
  const float* Wti = (const float*)d_in[17];
  const float* bti = (const float*)d_in[18];
  const float* Wto = (const float*)d_in[19];
  const float* bto = (const float*)d_in[20];

  double* wsd = (double*)d_ws;
  double4* sqd4 = (double4*)wsd;             // 65536 doubles
  double4* skd4 = (double4*)(wsd + 65536);   // 65536 doubles
  double* wphid = wsd + 131072;              // 128
  double* wtaud = wsd + 131200;              // 128
  double* ccd   = wsd + 131328;              // 2 (pad to 131332)
  float* fs = (float*)(wsd + 131332);
  float* Qf = fs;                  // 1,048,576 floats
  float* Kf = fs + 1048576;
  float* Vf = fs + 2097152;
  float* Cf = fs + 3145728;
  float* Sc = fs + 4194304;        // 16,777,216 floats (scores, 64 MB)
  const size_t need = (size_t)131332 * 8 + (size_t)(4194304 + 16777216) * 4;

  hipLaunchKernelGGL(k_collapse64, dim3(17), dim3(256), 0, stream,
                     Wpi, bpi, Wpo, bpo, Wti, bti, Wto, bto, wphid, wtaud, ccd);
  hipLaunchKernelGGL(k_gemm_qkv, dim3(24, 32), dim3(256), 0, stream,
                     x, Wq, bq, Wk, bk, Wv, bv, Qf, Kf, Vf);
  hipLaunchKernelGGL(k_tokscal64, dim3(NTOK / 256), dim3(256), 0, stream,
                     Qf, Kf, wphid, Wta, Wtb, wtaud, sqd4, skd4);
  if (ws_size >= need) {
    hipLaunchKernelGGL(k_score, dim3(8, 8, 16), dim3(256), 0, stream, Qf, Kf, Sc);
    hipLaunchKernelGGL(k_topk, dim3(NTOK / 4), dim3(256), 0, stream,
                       Sc, Vf, sqd4, skd4, ccd, bta, btb, Cf);
  } else {
    hipLaunchKernelGGL(k_attn, dim3(TT / 8, NBH), dim3(256), 0, stream,
                       Qf, Kf, Vf, sqd4, skd4, ccd, bta, btb, Cf);
  }
  hipLaunchKernelGGL(k_gemm, dim3(8, 32), dim3(256), 0, stream,
                     Cf, Wo, bo, (float*)d_out, 0);
}